// Round 8
// baseline (103.111 us; speedup 1.0000x reference)
//
#include <hip/hip_runtime.h>
#include <type_traits>

// Shapes (fixed by the problem)
#define Bn 8
#define Tn 2048
#define Cn 1024
#define Hn 128
#define Mn (Bn*Tn)   // 16384

typedef __attribute__((ext_vector_type(4))) float f32x4;
typedef __attribute__((ext_vector_type(2))) float f32x2;
typedef __attribute__((ext_vector_type(16))) float f32x16;
typedef __attribute__((ext_vector_type(8))) short s16x8;
typedef __attribute__((ext_vector_type(4))) int i32x4;
typedef __attribute__((ext_vector_type(2))) int i32x2;
typedef unsigned int u32;

__device__ __forceinline__ unsigned short f2bf(float f) {
  union { float f; unsigned u; } v; v.f = f;
  unsigned r = v.u + 0x7FFFu + ((v.u >> 16) & 1u);   // RNE
  return (unsigned short)(r >> 16);
}

__device__ __forceinline__ unsigned cvtpk(float lo, float hi) {
  unsigned r;
  asm("v_cvt_pk_bf16_f32 %0, %1, %2" : "=v"(r) : "v"(lo), "v"(hi));
  return r;
}

// swap32(a,b): r0 = {a.lanes[0:31], b.lanes[0:31]}, r1 = {a.lanes[32:63], b.lanes[32:63]}
__device__ __forceinline__ i32x2 swap32(int a, int b) {
#if __has_builtin(__builtin_amdgcn_permlane32_swap)
  return __builtin_amdgcn_permlane32_swap(a, b, false, false);
#else
  int ax = __shfl_xor(a, 32), bx = __shfl_xor(b, 32);
  i32x2 r;
  r[0] = (threadIdx.x & 32) ? bx : a;
  r[1] = (threadIdx.x & 32) ? b : ax;
  return r;
#endif
}

__device__ __forceinline__ void gl_lds16(const void* g, void* l) {
  __builtin_amdgcn_global_load_lds((const __attribute__((address_space(1))) u32*)g,
                                   (__attribute__((address_space(3))) u32*)l, 16, 0, 0);
}

// ---------------------------------------------------------------------------
// Kernel 1: W [C,H] fp32 -> Wt [3][H][C] = [384][1024] bf16 (Wq scaled by 1/32)
// ---------------------------------------------------------------------------
__global__ __launch_bounds__(256) void prep_wt(const float* __restrict__ Wq,
                                               const float* __restrict__ Wk,
                                               const float* __restrict__ Wv,
                                               unsigned short* __restrict__ Wt) {
  __shared__ float tile[64][33];
  const int w = blockIdx.z;
  const float* W = (w == 0) ? Wq : (w == 1) ? Wk : Wv;
  const float scale = (w == 0) ? 0.03125f : 1.0f;   // C^-0.5 folded into Wq (exact pow2)
  const int c0 = blockIdx.x * 64, h0 = blockIdx.y * 32;
  const int tid = threadIdx.x;
  const int hl = tid & 31, cg = tid >> 5;
#pragma unroll
  for (int i = 0; i < 8; i++) {
    int cl = cg * 8 + i;
    tile[cl][hl] = W[(c0 + cl) * Hn + h0 + hl];
  }
  __syncthreads();
  const int cl2 = tid & 63, hg = tid >> 6;
#pragma unroll
  for (int i = 0; i < 8; i++) {
    int hl2 = hg * 8 + i;
    Wt[(size_t)(w * Hn + h0 + hl2) * Cn + c0 + cl2] = f2bf(tile[cl2][hl2] * scale);
  }
}

// ---------------------------------------------------------------------------
// Kernel 2: FUSED QKV projection, v3. BM=64, BN=192 (N-split x2), BK=64,
// 4 waves (2m x 2n, 32x96/wave). B-fragments loaded DIRECTLY from global
// (Wt is L2-resident) -- no B staging, no gl_lds, no barrier coupling.
// A (x fp32->bf16) reg-staged 2 STEPS AHEAD into double-buffered LDS;
// one barrier per K-step. XCD-aware block map: the 2 n-splits of an
// m-stripe run temporally adjacent on the same XCD (x L2-hit on 2nd read).
// q,k -> [b][t][h]; v -> [b][h][t].
// ---------------------------------------------------------------------------
__global__ __launch_bounds__(256, 2) void proj_fused(const float* __restrict__ x,
                                                     const unsigned short* __restrict__ Wt,
                                                     unsigned short* __restrict__ qkv) {
  __shared__ __align__(16) unsigned short Abuf[2][64 * 64];    // 2 x 8 KB
  const int tid = threadIdx.x;
  const int lane = tid & 63, wv = tid >> 6;   // 4 waves
  const int wm = wv >> 1, wn = wv & 1;        // wave tile: rows wm*32, cols wn*96
  const int l31 = lane & 31, hi = lane >> 5;

  // XCD-aware block map: 512 blocks -> (mstr 0..255, ny 0..1)
  const int bid = blockIdx.x;
  const int xcd = bid & 7, idx = bid >> 3;
  const int mstr = xcd + 8 * (idx >> 1);
  const int ny = idx & 1;
  const int bm = mstr * 64;
  const int bn = ny * 192;

  // per-lane B row bases (constant over t): n = bn + wn*96 + ni*32 + l31
  const unsigned short* bptr0 = Wt + (size_t)(bn + wn * 96 + 0 * 32 + l31) * Cn + hi * 8;
  const unsigned short* bptr1 = Wt + (size_t)(bn + wn * 96 + 1 * 32 + l31) * Cn + hi * 8;
  const unsigned short* bptr2 = Wt + (size_t)(bn + wn * 96 + 2 * 32 + l31) * Cn + hi * 8;

  f32x16 acc[3];
#pragma unroll
  for (int i = 0; i < 3; i++)
#pragma unroll
    for (int r = 0; r < 16; r++) acc[i][r] = 0.f;

  // A staging: thread handles rows r0=tid>>3 and r0+32, chunk s0=tid&7 (8 floats each)
  const int ar0 = tid >> 3, as0 = tid & 7;

  auto loadA = [&](int t, float4* R) {
    const int kk = (t <= 15 ? t : 15) * 64;
    const float* g0 = x + (size_t)(bm + ar0) * Cn + kk + as0 * 8;
    const float* g1 = x + (size_t)(bm + ar0 + 32) * Cn + kk + as0 * 8;
    R[0] = *(const float4*)g0;
    R[1] = *(const float4*)(g0 + 4);
    R[2] = *(const float4*)g1;
    R[3] = *(const float4*)(g1 + 4);
  };
  auto writeA = [&](int buf, const float4* R) {
    i32x4 w0 = {(int)cvtpk(R[0].x, R[0].y), (int)cvtpk(R[0].z, R[0].w),
                (int)cvtpk(R[1].x, R[1].y), (int)cvtpk(R[1].z, R[1].w)};
    i32x4 w1 = {(int)cvtpk(R[2].x, R[2].y), (int)cvtpk(R[2].z, R[2].w),
                (int)cvtpk(R[3].x, R[3].y), (int)cvtpk(R[3].z, R[3].w)};
    *(i32x4*)&Abuf[buf][ar0 * 64 + ((as0 ^ (ar0 & 7)) << 3)] = w0;
    *(i32x4*)&Abuf[buf][(ar0 + 32) * 64 + ((as0 ^ ((ar0 + 32) & 7)) << 3)] = w1;
  };

  float4 RA[4], RB[4];
  // prologue: RA=t0, RB=t1; publish t0
  loadA(0, RA);
  loadA(1, RB);
  writeA(0, RA);
  __syncthreads();

  const int arow = wm * 32 + l31;

  auto body = [&](int t, auto PC) {
    constexpr int P = decltype(PC)::value;
    const bool more = (t < 15);
    // issue A loads for t+2 into the set freed by last step's writeA
    if constexpr (P == 0) loadA(t + 2, RA); else loadA(t + 2, RB);
    // A fragments from LDS buf P
    s16x8 aF[4];
#pragma unroll
    for (int ks = 0; ks < 4; ks++)
      aF[ks] = *(const s16x8*)&Abuf[P][arow * 64 + (((ks * 2 + hi) ^ (arow & 7)) << 3)];
    // MFMA with direct-global B fragments (L2-resident Wt)
    const size_t co = (size_t)t * 64;
    __builtin_amdgcn_s_setprio(1);
#pragma unroll
    for (int ks = 0; ks < 4; ks++) {
      s16x8 b0 = *(const s16x8*)(bptr0 + co + ks * 16);
      s16x8 b1 = *(const s16x8*)(bptr1 + co + ks * 16);
      s16x8 b2 = *(const s16x8*)(bptr2 + co + ks * 16);
      acc[0] = __builtin_amdgcn_mfma_f32_32x32x16_bf16(aF[ks], b0, acc[0], 0, 0, 0);
      acc[1] = __builtin_amdgcn_mfma_f32_32x32x16_bf16(aF[ks], b1, acc[1], 0, 0, 0);
      acc[2] = __builtin_amdgcn_mfma_f32_32x32x16_bf16(aF[ks], b2, acc[2], 0, 0, 0);
    }
    __builtin_amdgcn_s_setprio(0);
    if (more) {
      // publish t+1 (loaded 2 steps ago into the OTHER set)
      if constexpr (P == 0) writeA(P ^ 1, RB); else writeA(P ^ 1, RA);
      __syncthreads();
    }
  };

#pragma unroll 2
  for (int t = 0; t < 16; t += 2) {
    body(t, std::integral_constant<int, 0>{});
    body(t + 1, std::integral_constant<int, 1>{});
  }

  // epilogue: D layout col=l31, row=(r&3)+8*(r>>2)+4*hi
#pragma unroll
  for (int ni = 0; ni < 3; ni++) {
    const int cb = ny * 6 + wn * 3 + ni;      // 32-col block 0..11
    if (cb < 8) {                             // q (0-3) / k (4-7): [b][t][h]
      const int w = cb >> 2;
      const int h = (cb & 3) * 32 + l31;
      unsigned short* o = qkv + (size_t)w * ((size_t)Mn * Hn);
#pragma unroll
      for (int r = 0; r < 16; r++) {
        int m = bm + wm * 32 + (r & 3) + 8 * (r >> 2) + 4 * hi;
        o[(size_t)m * Hn + h] = f2bf(acc[ni][r]);
      }
    } else {                                  // v: transposed [b][h][t]
      const int h = (cb - 8) * 32 + l31;
      const int bb = bm >> 11;
      const int tl0 = (bm & 2047) + wm * 32;
      unsigned short* vt = qkv + (size_t)2 * Mn * Hn + (size_t)bb * (Hn * Tn) + (size_t)h * Tn;
#pragma unroll
      for (int r = 0; r < 16; r++)
        vt[tl0 + (r & 3) + 8 * (r >> 2) + 4 * hi] = f2bf(acc[ni][r]);
    }
  }
}

// ---------------------------------------------------------------------------
// Kernel 3: causal flash attention. 4 waves/block, 128 q-rows/block (32/wave),
// KVBLK=64 staged in LDS (XOR-swizzled, global_load_lds, double-buffered,
// 2-phase). Swapped 32x32 MFMA, in-register softmax. KV-split S chunks with
// complementary q-tile pairing for load balance. Partials to workspace.
// ---------------------------------------------------------------------------
__global__ __launch_bounds__(256, 2) void attn_fwd(const unsigned short* __restrict__ qkv,
                                                   float* __restrict__ o_part,
                                                   float* __restrict__ ml,
                                                   int sshift) {
  __shared__ __align__(16) unsigned short Kl[2][64 * 128];  // [kv][h] 16KB x2
  __shared__ __align__(16) unsigned short Vl[2][128 * 64];  // [h][kv] 16KB x2

  const int bid = blockIdx.x;
  const int b = bid & 7;                    // batch -> XCD pin
  const int r = bid >> 3;
  const int jj = r & 15;
  const int sp = r >> 4;
  const int S = 1 << sshift;
  const int j = (S > 1 && sp >= (S >> 1)) ? (15 - jj) : jj;   // complementary pairing
  const int s = sp;

  const int tid = threadIdx.x;
  const int lane = tid & 63, wv = tid >> 6;   // 4 waves
  const int l31 = lane & 31, hi = lane >> 5;

  const unsigned short* qb  = qkv + (size_t)b * (Tn * Hn);
  const unsigned short* kb  = qkv + (size_t)(Mn * Hn) + (size_t)b * (Tn * Hn);
  const unsigned short* vtb = qkv + (size_t)2 * (Mn * Hn) + (size_t)b * (Hn * Tn);

  const int qrow0 = j * 128 + wv * 32;      // this wave's 32 q-rows
  const int qg = qrow0 + l31;               // this lane's q-row

  const int ntt = (j + 1) * 2;              // kv tiles of 64 for this q-tile
  const int tlo = (s * ntt) >> sshift;
  const int thi = ((s + 1) * ntt) >> sshift;

  f32x16 oT[4];
#pragma unroll
  for (int i = 0; i < 4; i++)
#pragma unroll
    for (int q = 0; q < 16; q++) oT[i][q] = 0.f;
  float m_ = -1e30f, l_ = 0.f;

  auto stage = [&](int buf, int tile) {
    const int kvb0 = tile * 64;
#pragma unroll
    for (int i = 0; i < 4; i++) {
      int r0 = wv * 16 + i * 4;
      int row = r0 + (lane >> 4);
      int ch = lane & 15;
      const unsigned short* src = kb + (size_t)(kvb0 + row) * Hn + ((ch ^ (row & 7)) << 3);
      gl_lds16(src, &Kl[buf][r0 * 128]);
    }
#pragma unroll
    for (int i = 0; i < 4; i++) {
      int r0 = wv * 32 + i * 8;
      int row = r0 + (lane >> 3);
      int ch = lane & 7;
      const unsigned short* src = vtb + (size_t)row * Tn + kvb0 + ((ch ^ (row & 7)) << 3);
      gl_lds16(src, &Vl[buf][r0 * 64]);
    }
  };

  if (tlo < thi) {
    // Q B-fragments: n=q=l31, k = hs*16 + hi*8 + jx
    s16x8 qB[8];
#pragma unroll
    for (int hs = 0; hs < 8; hs++)
      qB[hs] = *(const s16x8*)(qb + (size_t)qg * Hn + hs * 16 + hi * 8);

    stage(0, tlo);
    asm volatile("s_waitcnt vmcnt(0)");
    __syncthreads();
    int buf = 0;

    for (int t = tlo; t < thi; t++) {
      if (t + 1 < thi) stage(buf ^ 1, t + 1);   // loads in flight over compute
      const int kvb = t * 64;
      if (kvb < qrow0 + 32) {                   // wave not fully above diagonal
        const unsigned short* Kb = &Kl[buf][0];
        // ---- S^T = K Q^T (two 32-kv halves) ----
        f32x16 sv0, sv1;
#pragma unroll
        for (int q = 0; q < 16; q++) { sv0[q] = 0.f; sv1[q] = 0.f; }
        __builtin_amdgcn_s_setprio(1);
        {
          const int row = l31;
#pragma unroll
          for (int hs = 0; hs < 8; hs++) {
            s16x8 kf = *(const s16x8*)&Kb[row * 128 + (((hs * 2 + hi) ^ (row & 7)) << 3)];
            sv0 = __builtin_amdgcn_mfma_f32_32x32x16_bf16(kf, qB[hs], sv0, 0, 0, 0);
          }
        }
        {
          const int row = 32 + l31;
#pragma unroll
          for (int hs = 0; hs < 8; hs++) {
            s16x8 kf = *(const s16x8*)&Kb[row * 128 + (((hs * 2 + hi) ^ (row & 7)) << 3)];
            sv1 = __builtin_amdgcn_mfma_f32_32x32x16_bf16(kf, qB[hs], sv1, 0, 0, 0);
          }
        }
        __builtin_amdgcn_s_setprio(0);
        // ---- causal mask (diagonal-adjacent tiles only) ----
        if (kvb + 63 > qrow0) {
#pragma unroll
          for (int q = 0; q < 16; q++) {
            int kr = (q & 3) + 8 * (q >> 2) + 4 * hi;
            if (kvb + kr > qg) sv0[q] = -1e30f;
            if (kvb + 32 + kr > qg) sv1[q] = -1e30f;
          }
        }
        // ---- online softmax (row = per-lane) ----
        float om = sv0[0];
#pragma unroll
        for (int q = 1; q < 16; q++) om = fmaxf(om, sv0[q]);
#pragma unroll
        for (int q = 0; q < 16; q++) om = fmaxf(om, sv1[q]);
        i32x2 mx = swap32(__builtin_bit_cast(int, om), __builtin_bit_cast(int, om));
        float pm = __builtin_bit_cast(float, hi ? mx[0] : mx[1]);
        float tmax = fmaxf(om, pm);
        if (__any(tmax > m_ + 8.f)) {           // deferred rescale (T13)
          float mn = fmaxf(m_, tmax);
          float sc = __expf(m_ - mn);
          m_ = mn; l_ *= sc;
#pragma unroll
          for (int i = 0; i < 4; i++)
#pragma unroll
            for (int q = 0; q < 16; q++) oT[i][q] *= sc;
        }
        float osum = 0.f;
#pragma unroll
        for (int q = 0; q < 16; q++) { sv0[q] = __expf(sv0[q] - m_); osum += sv0[q]; }
#pragma unroll
        for (int q = 0; q < 16; q++) { sv1[q] = __expf(sv1[q] - m_); osum += sv1[q]; }
        i32x2 sx = swap32(__builtin_bit_cast(int, osum), __builtin_bit_cast(int, osum));
        float psum = __builtin_bit_cast(float, hi ? sx[0] : sx[1]);
        l_ += osum + psum;
        // ---- pack P^T to bf16 B-fragments (T12) ----
        s16x8 pB[4];
        {
          unsigned PK[8];
#pragma unroll
          for (int n = 0; n < 8; n++) PK[n] = cvtpk(sv0[2 * n], sv0[2 * n + 1]);
          i32x2 e0 = swap32((int)PK[0], (int)PK[2]);
          i32x2 e1 = swap32((int)PK[1], (int)PK[3]);
          i32x2 e2 = swap32((int)PK[4], (int)PK[6]);
          i32x2 e3 = swap32((int)PK[5], (int)PK[7]);
          i32x4 w0 = {e0[0], e1[0], e0[1], e1[1]};
          i32x4 w1 = {e2[0], e3[0], e2[1], e3[1]};
          pB[0] = __builtin_bit_cast(s16x8, w0);
          pB[1] = __builtin_bit_cast(s16x8, w1);
        }
        {
          unsigned PK[8];
#pragma unroll
          for (int n = 0; n < 8; n++) PK[n] = cvtpk(sv1[2 * n], sv1[2 * n + 1]);
          i32x2 e0 = swap32((int)PK[0], (int)PK[2]);
          i32x2 e1 = swap32((int)PK[1], (int)PK[3]);
          i32x2 e2 = swap32((int)PK[4], (int)PK[6]);
          i32x2 e3 = swap32((int)PK[5], (int)PK[7]);
          i32x4 w0 = {e0[0], e1[0], e0[1], e1[1]};
          i32x4 w1 = {e2[0], e3[0], e2[1], e3[1]};
          pB[2] = __builtin_bit_cast(s16x8, w0);
          pB[3] = __builtin_bit_cast(s16x8, w1);
        }
        // ---- O^T += V^T P^T ----
        __builtin_amdgcn_s_setprio(1);
#pragma unroll
        for (int hsl = 0; hsl < 4; hsl++) {
          const int row = hsl * 32 + l31;
#pragma unroll
          for (int ks = 0; ks < 4; ks++) {
            s16x8 vf = *(const s16x8*)&Vl[buf][row * 64 + (((ks * 2 + hi) ^ (row & 7)) << 3)];
            oT[hsl] = __builtin_amdgcn_mfma_f32_32x32x16_bf16(vf, pB[ks], oT[hsl], 0, 0, 0);
          }
        }
        __builtin_amdgcn_s_setprio(0);
      }
      asm volatile("s_waitcnt vmcnt(0)");       // staged t+1 landed
      __syncthreads();                          // cur fully consumed by all waves
      buf ^= 1;
    }
  }

  // epilogue: o_part[s][row][h], h = hsl*32 + (q&3) + 8*(q>>2) + 4*hi
  float* orow = o_part + (size_t)s * ((size_t)Mn * Hn) + (size_t)(b * Tn + qg) * Hn;
#pragma unroll
  for (int hsl = 0; hsl < 4; hsl++)
#pragma unroll
    for (int g = 0; g < 4; g++) {
      f32x4 st = {oT[hsl][4 * g + 0], oT[hsl][4 * g + 1], oT[hsl][4 * g + 2], oT[hsl][4 * g + 3]};
      *(f32x4*)(orow + hsl * 32 + g * 8 + hi * 4) = st;
    }
  if (lane < 32) {
    f32x2 w = {m_, l_};
    *(f32x2*)(ml + (size_t)s * (Mn * 2) + (size_t)(b * Tn + qg) * 2) = w;
  }
}

// ---------------------------------------------------------------------------
// Kernel 4: combine KV-split partials.
// ---------------------------------------------------------------------------
__global__ __launch_bounds__(256) void combine(const float* __restrict__ o_part,
                                               const float* __restrict__ ml,
                                               float* __restrict__ out, int S) {
  const int q = blockIdx.x * 2 + (threadIdx.x >> 7);
  const int h = threadIdx.x & 127;
  float M = -1e30f;
  for (int s = 0; s < S; s++) M = fmaxf(M, ml[(size_t)s * (Mn * 2) + q * 2]);
  float L = 0.f, acc = 0.f;
  for (int s = 0; s < S; s++) {
    float ms = ml[(size_t)s * (Mn * 2) + q * 2];
    float ls = ml[(size_t)s * (Mn * 2) + q * 2 + 1];
    float w = __expf(ms - M);
    L += ls * w;
    acc += o_part[(size_t)s * ((size_t)Mn * Hn) + (size_t)q * Hn + h] * w;
  }
  out[(size_t)q * Hn + h] = acc / L;
}

// ---------------------------------------------------------------------------
extern "C" void kernel_launch(void* const* d_in, const int* in_sizes, int n_in,
                              void* d_out, int out_size, void* d_ws, size_t ws_size,
                              hipStream_t stream) {
  const float* x  = (const float*)d_in[0];
  const float* Wk = (const float*)d_in[1];
  const float* Wq = (const float*)d_in[2];
  const float* Wv = (const float*)d_in[3];
  float* out = (float*)d_out;

  char* ws = (char*)d_ws;
  const size_t wt_b  = 786432;                      // 3*128*1024*2
  const size_t qkv_b = (size_t)3 * Mn * Hn * 2;     // 12.58 MB
  const size_t base  = wt_b + qkv_b;
  const size_t per   = (size_t)Mn * Hn * 4 + (size_t)Mn * 8;
  int sshift = (ws_size >= base + 4 * per) ? 2 : (ws_size >= base + 2 * per) ? 1 : 0;
  const int S = 1 << sshift;

  unsigned short* Wt  = (unsigned short*)ws;
  unsigned short* qkv = (unsigned short*)(ws + wt_b);
  float* o_part = (float*)(ws + base);
  float* mlp    = (float*)(ws + base + (size_t)S * Mn * Hn * 4);

  prep_wt<<<dim3(16, 4, 3), 256, 0, stream>>>(Wq, Wk, Wv, Wt);
  proj_fused<<<512, 256, 0, stream>>>(x, Wt, qkv);
  attn_fwd<<<128 * S, 256, 0, stream>>>(qkv, o_part, mlp, sshift);
  combine<<<Mn / 2, 256, 0, stream>>>(o_part, mlp, out, S);
}

// Round 9
// 67.532 us; speedup vs baseline: 1.5269x; 1.5269x over previous
//
#include <hip/hip_runtime.h>
#include <type_traits>

// Shapes (fixed by the problem)
#define Bn 8
#define Tn 2048
#define Cn 1024
#define Hn 128
#define Mn (Bn*Tn)   // 16384

typedef __attribute__((ext_vector_type(4))) float f32x4;
typedef __attribute__((ext_vector_type(2))) float f32x2;
typedef __attribute__((ext_vector_type(16))) float f32x16;
typedef __attribute__((ext_vector_type(8))) short s16x8;
typedef __attribute__((ext_vector_type(4))) int i32x4;
typedef __attribute__((ext_vector_type(2))) int i32x2;
typedef unsigned int u32;

__device__ __forceinline__ unsigned short f2bf(float f) {
  union { float f; unsigned u; } v; v.f = f;
  unsigned r = v.u + 0x7FFFu + ((v.u >> 16) & 1u);   // RNE
  return (unsigned short)(r >> 16);
}

__device__ __forceinline__ unsigned cvtpk(float lo, float hi) {
  unsigned r;
  asm("v_cvt_pk_bf16_f32 %0, %1, %2" : "=v"(r) : "v"(lo), "v"(hi));
  return r;
}

// swap32(a,b): r0 = {a.lanes[0:31], b.lanes[0:31]}, r1 = {a.lanes[32:63], b.lanes[32:63]}
__device__ __forceinline__ i32x2 swap32(int a, int b) {
#if __has_builtin(__builtin_amdgcn_permlane32_swap)
  return __builtin_amdgcn_permlane32_swap(a, b, false, false);
#else
  int ax = __shfl_xor(a, 32), bx = __shfl_xor(b, 32);
  i32x2 r;
  r[0] = (threadIdx.x & 32) ? bx : a;
  r[1] = (threadIdx.x & 32) ? b : ax;
  return r;
#endif
}

__device__ __forceinline__ void gl_lds16(const void* g, void* l) {
  __builtin_amdgcn_global_load_lds((const __attribute__((address_space(1))) u32*)g,
                                   (__attribute__((address_space(3))) u32*)l, 16, 0, 0);
}

// ---------------------------------------------------------------------------
// Kernel 1: W [C,H] fp32 -> Wt [3][H][C] = [384][1024] bf16 (Wq scaled by 1/32)
// ---------------------------------------------------------------------------
__global__ __launch_bounds__(256) void prep_wt(const float* __restrict__ Wq,
                                               const float* __restrict__ Wk,
                                               const float* __restrict__ Wv,
                                               unsigned short* __restrict__ Wt) {
  __shared__ float tile[64][33];
  const int w = blockIdx.z;
  const float* W = (w == 0) ? Wq : (w == 1) ? Wk : Wv;
  const float scale = (w == 0) ? 0.03125f : 1.0f;   // C^-0.5 folded into Wq (exact pow2)
  const int c0 = blockIdx.x * 64, h0 = blockIdx.y * 32;
  const int tid = threadIdx.x;
  const int hl = tid & 31, cg = tid >> 5;
#pragma unroll
  for (int i = 0; i < 8; i++) {
    int cl = cg * 8 + i;
    tile[cl][hl] = W[(c0 + cl) * Hn + h0 + hl];
  }
  __syncthreads();
  const int cl2 = tid & 63, hg = tid >> 6;
#pragma unroll
  for (int i = 0; i < 8; i++) {
    int hl2 = hg * 8 + i;
    Wt[(size_t)(w * Hn + h0 + hl2) * Cn + c0 + cl2] = f2bf(tile[cl2][hl2] * scale);
  }
}

// ---------------------------------------------------------------------------
// Kernel 2: FUSED QKV projection, v5 = round-4 structure + counted-vmcnt
// raw-barrier schedule (T4). BM=64, BN=384, BK=64, 8 waves (2m x 4n, 32x96).
// Per step: issue t+1 staging (2 A-loads + 6 B gl_lds), then
// s_waitcnt vmcnt(8) (prev-step staging only) + raw s_barrier -> the
// just-issued 8 loads stay in flight across the barrier (no vmcnt(0) drain).
// q,k -> [b][t][h]; v -> [b][h][t].
// ---------------------------------------------------------------------------
__global__ __launch_bounds__(512, 1) void proj_fused(const float* __restrict__ x,
                                                     const unsigned short* __restrict__ Wt,
                                                     unsigned short* __restrict__ qkv) {
  __shared__ __align__(16) unsigned short Abuf[2][64 * 64];    // 2 x 8 KB
  __shared__ __align__(16) unsigned short Bbuf[2][384 * 64];   // 2 x 48 KB
  const int tid = threadIdx.x;
  const int lane = tid & 63, wv = tid >> 6;   // 8 waves
  const int wm = wv >> 2, wn = wv & 3;        // wave tile: rows wm*32, cols wn*96
  const int l31 = lane & 31, hi = lane >> 5;
  const int bm = blockIdx.x * 64;

  // A-staging geometry (512 threads, 64x64 tile, 8 fp32 each)
  const int ar = tid >> 3;                    // row 0..63
  const int as = tid & 7;                     // 8-float chunk

  f32x16 acc[3];
#pragma unroll
  for (int i = 0; i < 3; i++)
#pragma unroll
    for (int r = 0; r < 16; r++) acc[i][r] = 0.f;

  auto stageB = [&](int buf, int kk) {
#pragma unroll
    for (int i = 0; i < 6; i++) {
      int r0 = wv * 48 + i * 8;
      int n = r0 + (lane >> 3);
      const unsigned short* src = Wt + (size_t)n * Cn + kk + (((lane & 7) ^ (n & 7)) << 3);
      gl_lds16(src, &Bbuf[buf][r0 * 64]);     // dest wave-uniform; +lane*16B implicit
    }
  };
  auto loadA = [&](int kk, float4& v0, float4& v1) {
    const float* g = x + (size_t)(bm + ar) * Cn + kk + as * 8;
    v0 = *(const float4*)g;
    v1 = *(const float4*)(g + 4);
  };
  auto writeA = [&](int buf, float4 v0, float4 v1) {
    i32x4 w = {(int)cvtpk(v0.x, v0.y), (int)cvtpk(v0.z, v0.w),
               (int)cvtpk(v1.x, v1.y), (int)cvtpk(v1.z, v1.w)};
    *(i32x4*)&Abuf[buf][ar * 64 + ((as ^ (ar & 7)) << 3)] = w;
  };

  // prologue: stage K-step 0 (2 A loads + 6 gl_lds; compiler waits A before write)
  {
    float4 a0, a1;
    loadA(0, a0, a1);
    stageB(0, 0);
    writeA(0, a0, a1);
  }

  const int arow = wm * 32 + l31;

  auto body = [&](int t, auto PC) {
    constexpr int P = decltype(PC)::value;    // cur buffer
    const bool more = (t < 15);
    float4 a0, a1;
    if (more) {
      loadA((t + 1) * 64, a0, a1);            // 2 vm
      stageB(P ^ 1, (t + 1) * 64);            // 6 vm (gl_lds)
      // wait only ops OLDER than my 8 (= prev step's staging); publish A writes
      asm volatile("s_waitcnt vmcnt(8) lgkmcnt(0)" ::: "memory");
    } else {
      asm volatile("s_waitcnt vmcnt(0) lgkmcnt(0)" ::: "memory");
    }
    __builtin_amdgcn_s_barrier();             // raw barrier: no compiler vmcnt(0) drain
    __builtin_amdgcn_sched_barrier(0);
    // compute on buf P
    s16x8 aF[4];
#pragma unroll
    for (int ks = 0; ks < 4; ks++)
      aF[ks] = *(const s16x8*)&Abuf[P][arow * 64 + (((ks * 2 + hi) ^ (arow & 7)) << 3)];
    __builtin_amdgcn_s_setprio(1);
#pragma unroll
    for (int ks = 0; ks < 4; ks++)
#pragma unroll
      for (int ni = 0; ni < 3; ni++) {
        int brow = wn * 96 + ni * 32 + l31;
        s16x8 bF = *(const s16x8*)&Bbuf[P][brow * 64 + (((ks * 2 + hi) ^ (brow & 7)) << 3)];
        acc[ni] = __builtin_amdgcn_mfma_f32_32x32x16_bf16(aF[ks], bF, acc[ni], 0, 0, 0);
      }
    __builtin_amdgcn_s_setprio(0);
    if (more) writeA(P ^ 1, a0, a1);          // compiler inserts exact vmcnt for A loads
  };

  for (int t = 0; t < 16; t += 2) {
    body(t, std::integral_constant<int, 0>{});
    body(t + 1, std::integral_constant<int, 1>{});
  }

  // epilogue: D layout col=l31, row=(r&3)+8*(r>>2)+4*hi
#pragma unroll
  for (int ni = 0; ni < 3; ni++) {
    const int cb = wn * 3 + ni;               // 32-col block 0..11
    if (cb < 8) {                             // q (0-3) / k (4-7): [b][t][h]
      const int w = cb >> 2;
      const int h = (cb & 3) * 32 + l31;
      unsigned short* o = qkv + (size_t)w * ((size_t)Mn * Hn);
#pragma unroll
      for (int r = 0; r < 16; r++) {
        int m = bm + wm * 32 + (r & 3) + 8 * (r >> 2) + 4 * hi;
        o[(size_t)m * Hn + h] = f2bf(acc[ni][r]);
      }
    } else {                                  // v: transposed [b][h][t]
      const int h = (cb - 8) * 32 + l31;
      const int bb = bm >> 11;
      const int tl0 = (bm & 2047) + wm * 32;
      unsigned short* vt = qkv + (size_t)2 * Mn * Hn + (size_t)bb * (Hn * Tn) + (size_t)h * Tn;
#pragma unroll
      for (int r = 0; r < 16; r++)
        vt[tl0 + (r & 3) + 8 * (r >> 2) + 4 * hi] = f2bf(acc[ni][r]);
    }
  }
}

// ---------------------------------------------------------------------------
// Kernel 3: causal flash attention. 4 waves/block, 128 q-rows/block (32/wave),
// KVBLK=64 staged in LDS (XOR-swizzled, global_load_lds, double-buffered,
// 2-phase). Swapped 32x32 MFMA, in-register softmax. KV-split S chunks with
// complementary q-tile pairing for load balance. Partials to workspace.
// ---------------------------------------------------------------------------
__global__ __launch_bounds__(256, 2) void attn_fwd(const unsigned short* __restrict__ qkv,
                                                   float* __restrict__ o_part,
                                                   float* __restrict__ ml,
                                                   int sshift) {
  __shared__ __align__(16) unsigned short Kl[2][64 * 128];  // [kv][h] 16KB x2
  __shared__ __align__(16) unsigned short Vl[2][128 * 64];  // [h][kv] 16KB x2

  const int bid = blockIdx.x;
  const int b = bid & 7;                    // batch -> XCD pin
  const int r = bid >> 3;
  const int jj = r & 15;
  const int sp = r >> 4;
  const int S = 1 << sshift;
  const int j = (S > 1 && sp >= (S >> 1)) ? (15 - jj) : jj;   // complementary pairing
  const int s = sp;

  const int tid = threadIdx.x;
  const int lane = tid & 63, wv = tid >> 6;   // 4 waves
  const int l31 = lane & 31, hi = lane >> 5;

  const unsigned short* qb  = qkv + (size_t)b * (Tn * Hn);
  const unsigned short* kb  = qkv + (size_t)(Mn * Hn) + (size_t)b * (Tn * Hn);
  const unsigned short* vtb = qkv + (size_t)2 * (Mn * Hn) + (size_t)b * (Hn * Tn);

  const int qrow0 = j * 128 + wv * 32;      // this wave's 32 q-rows
  const int qg = qrow0 + l31;               // this lane's q-row

  const int ntt = (j + 1) * 2;              // kv tiles of 64 for this q-tile
  const int tlo = (s * ntt) >> sshift;
  const int thi = ((s + 1) * ntt) >> sshift;

  f32x16 oT[4];
#pragma unroll
  for (int i = 0; i < 4; i++)
#pragma unroll
    for (int q = 0; q < 16; q++) oT[i][q] = 0.f;
  float m_ = -1e30f, l_ = 0.f;

  auto stage = [&](int buf, int tile) {
    const int kvb0 = tile * 64;
#pragma unroll
    for (int i = 0; i < 4; i++) {
      int r0 = wv * 16 + i * 4;
      int row = r0 + (lane >> 4);
      int ch = lane & 15;
      const unsigned short* src = kb + (size_t)(kvb0 + row) * Hn + ((ch ^ (row & 7)) << 3);
      gl_lds16(src, &Kl[buf][r0 * 128]);
    }
#pragma unroll
    for (int i = 0; i < 4; i++) {
      int r0 = wv * 32 + i * 8;
      int row = r0 + (lane >> 3);
      int ch = lane & 7;
      const unsigned short* src = vtb + (size_t)row * Tn + kvb0 + ((ch ^ (row & 7)) << 3);
      gl_lds16(src, &Vl[buf][r0 * 64]);
    }
  };

  if (tlo < thi) {
    // Q B-fragments: n=q=l31, k = hs*16 + hi*8 + jx
    s16x8 qB[8];
#pragma unroll
    for (int hs = 0; hs < 8; hs++)
      qB[hs] = *(const s16x8*)(qb + (size_t)qg * Hn + hs * 16 + hi * 8);

    stage(0, tlo);
    asm volatile("s_waitcnt vmcnt(0)");
    __syncthreads();
    int buf = 0;

    for (int t = tlo; t < thi; t++) {
      if (t + 1 < thi) stage(buf ^ 1, t + 1);   // loads in flight over compute
      const int kvb = t * 64;
      if (kvb < qrow0 + 32) {                   // wave not fully above diagonal
        const unsigned short* Kb = &Kl[buf][0];
        // ---- S^T = K Q^T (two 32-kv halves) ----
        f32x16 sv0, sv1;
#pragma unroll
        for (int q = 0; q < 16; q++) { sv0[q] = 0.f; sv1[q] = 0.f; }
        __builtin_amdgcn_s_setprio(1);
        {
          const int row = l31;
#pragma unroll
          for (int hs = 0; hs < 8; hs++) {
            s16x8 kf = *(const s16x8*)&Kb[row * 128 + (((hs * 2 + hi) ^ (row & 7)) << 3)];
            sv0 = __builtin_amdgcn_mfma_f32_32x32x16_bf16(kf, qB[hs], sv0, 0, 0, 0);
          }
        }
        {
          const int row = 32 + l31;
#pragma unroll
          for (int hs = 0; hs < 8; hs++) {
            s16x8 kf = *(const s16x8*)&Kb[row * 128 + (((hs * 2 + hi) ^ (row & 7)) << 3)];
            sv1 = __builtin_amdgcn_mfma_f32_32x32x16_bf16(kf, qB[hs], sv1, 0, 0, 0);
          }
        }
        __builtin_amdgcn_s_setprio(0);
        // ---- causal mask (diagonal-adjacent tiles only) ----
        if (kvb + 63 > qrow0) {
#pragma unroll
          for (int q = 0; q < 16; q++) {
            int kr = (q & 3) + 8 * (q >> 2) + 4 * hi;
            if (kvb + kr > qg) sv0[q] = -1e30f;
            if (kvb + 32 + kr > qg) sv1[q] = -1e30f;
          }
        }
        // ---- online softmax (row = per-lane) ----
        float om = sv0[0];
#pragma unroll
        for (int q = 1; q < 16; q++) om = fmaxf(om, sv0[q]);
#pragma unroll
        for (int q = 0; q < 16; q++) om = fmaxf(om, sv1[q]);
        i32x2 mx = swap32(__builtin_bit_cast(int, om), __builtin_bit_cast(int, om));
        float pm = __builtin_bit_cast(float, hi ? mx[0] : mx[1]);
        float tmax = fmaxf(om, pm);
        if (__any(tmax > m_ + 8.f)) {           // deferred rescale (T13)
          float mn = fmaxf(m_, tmax);
          float sc = __expf(m_ - mn);
          m_ = mn; l_ *= sc;
#pragma unroll
          for (int i = 0; i < 4; i++)
#pragma unroll
            for (int q = 0; q < 16; q++) oT[i][q] *= sc;
        }
        float osum = 0.f;
#pragma unroll
        for (int q = 0; q < 16; q++) { sv0[q] = __expf(sv0[q] - m_); osum += sv0[q]; }
#pragma unroll
        for (int q = 0; q < 16; q++) { sv1[q] = __expf(sv1[q] - m_); osum += sv1[q]; }
        i32x2 sx = swap32(__builtin_bit_cast(int, osum), __builtin_bit_cast(int, osum));
        float psum = __builtin_bit_cast(float, hi ? sx[0] : sx[1]);
        l_ += osum + psum;
        // ---- pack P^T to bf16 B-fragments (T12) ----
        s16x8 pB[4];
        {
          unsigned PK[8];
#pragma unroll
          for (int n = 0; n < 8; n++) PK[n] = cvtpk(sv0[2 * n], sv0[2 * n + 1]);
          i32x2 e0 = swap32((int)PK[0], (int)PK[2]);
          i32x2 e1 = swap32((int)PK[1], (int)PK[3]);
          i32x2 e2 = swap32((int)PK[4], (int)PK[6]);
          i32x2 e3 = swap32((int)PK[5], (int)PK[7]);
          i32x4 w0 = {e0[0], e1[0], e0[1], e1[1]};
          i32x4 w1 = {e2[0], e3[0], e2[1], e3[1]};
          pB[0] = __builtin_bit_cast(s16x8, w0);
          pB[1] = __builtin_bit_cast(s16x8, w1);
        }
        {
          unsigned PK[8];
#pragma unroll
          for (int n = 0; n < 8; n++) PK[n] = cvtpk(sv1[2 * n], sv1[2 * n + 1]);
          i32x2 e0 = swap32((int)PK[0], (int)PK[2]);
          i32x2 e1 = swap32((int)PK[1], (int)PK[3]);
          i32x2 e2 = swap32((int)PK[4], (int)PK[6]);
          i32x2 e3 = swap32((int)PK[5], (int)PK[7]);
          i32x4 w0 = {e0[0], e1[0], e0[1], e1[1]};
          i32x4 w1 = {e2[0], e3[0], e2[1], e3[1]};
          pB[2] = __builtin_bit_cast(s16x8, w0);
          pB[3] = __builtin_bit_cast(s16x8, w1);
        }
        // ---- O^T += V^T P^T ----
        __builtin_amdgcn_s_setprio(1);
#pragma unroll
        for (int hsl = 0; hsl < 4; hsl++) {
          const int row = hsl * 32 + l31;
#pragma unroll
          for (int ks = 0; ks < 4; ks++) {
            s16x8 vf = *(const s16x8*)&Vl[buf][row * 64 + (((ks * 2 + hi) ^ (row & 7)) << 3)];
            oT[hsl] = __builtin_amdgcn_mfma_f32_32x32x16_bf16(vf, pB[ks], oT[hsl], 0, 0, 0);
          }
        }
        __builtin_amdgcn_s_setprio(0);
      }
      asm volatile("s_waitcnt vmcnt(0)");       // staged t+1 landed
      __syncthreads();                          // cur fully consumed by all waves
      buf ^= 1;
    }
  }

  // epilogue: o_part[s][row][h], h = hsl*32 + (q&3) + 8*(q>>2) + 4*hi
  float* orow = o_part + (size_t)s * ((size_t)Mn * Hn) + (size_t)(b * Tn + qg) * Hn;
#pragma unroll
  for (int hsl = 0; hsl < 4; hsl++)
#pragma unroll
    for (int g = 0; g < 4; g++) {
      f32x4 st = {oT[hsl][4 * g + 0], oT[hsl][4 * g + 1], oT[hsl][4 * g + 2], oT[hsl][4 * g + 3]};
      *(f32x4*)(orow + hsl * 32 + g * 8 + hi * 4) = st;
    }
  if (lane < 32) {
    f32x2 w = {m_, l_};
    *(f32x2*)(ml + (size_t)s * (Mn * 2) + (size_t)(b * Tn + qg) * 2) = w;
  }
}

// ---------------------------------------------------------------------------
// Kernel 4: combine KV-split partials.
// ---------------------------------------------------------------------------
__global__ __launch_bounds__(256) void combine(const float* __restrict__ o_part,
                                               const float* __restrict__ ml,
                                               float* __restrict__ out, int S) {
  const int q = blockIdx.x * 2 + (threadIdx.x >> 7);
  const int h = threadIdx.x & 127;
  float M = -1e30f;
  for (int s = 0; s < S; s++) M = fmaxf(M, ml[(size_t)s * (Mn * 2) + q * 2]);
  float L = 0.f, acc = 0.f;
  for (int s = 0; s < S; s++) {
    float ms = ml[(size_t)s * (Mn * 2) + q * 2];
    float ls = ml[(size_t)s * (Mn * 2) + q * 2 + 1];
    float w = __expf(ms - M);
    L += ls * w;
    acc += o_part[(size_t)s * ((size_t)Mn * Hn) + (size_t)q * Hn + h] * w;
  }
  out[(size_t)q * Hn + h] = acc / L;
}

// ---------------------------------------------------------------------------
extern "C" void kernel_launch(void* const* d_in, const int* in_sizes, int n_in,
                              void* d_out, int out_size, void* d_ws, size_t ws_size,
                              hipStream_t stream) {
  const float* x  = (const float*)d_in[0];
  const float* Wk = (const float*)d_in[1];
  const float* Wq = (const float*)d_in[2];
  const float* Wv = (const float*)d_in[3];
  float* out = (float*)d_out;

  char* ws = (char*)d_ws;
  const size_t wt_b  = 786432;                      // 3*128*1024*2
  const size_t qkv_b = (size_t)3 * Mn * Hn * 2;     // 12.58 MB
  const size_t base  = wt_b + qkv_b;
  const size_t per   = (size_t)Mn * Hn * 4 + (size_t)Mn * 8;
  int sshift = (ws_size >= base + 4 * per) ? 2 : (ws_size >= base + 2 * per) ? 1 : 0;
  const int S = 1 << sshift;

  unsigned short* Wt  = (unsigned short*)ws;
  unsigned short* qkv = (unsigned short*)(ws + wt_b);
  float* o_part = (float*)(ws + base);
  float* mlp    = (float*)(ws + base + (size_t)S * Mn * Hn * 4);

  prep_wt<<<dim3(16, 4, 3), 256, 0, stream>>>(Wq, Wk, Wv, Wt);
  proj_fused<<<256, 512, 0, stream>>>(x, Wt, qkv);
  attn_fwd<<<128 * S, 256, 0, stream>>>(qkv, o_part, mlp, sshift);
  combine<<<Mn / 2, 256, 0, stream>>>(o_part, mlp, out, S);
}

// Round 10
// 66.955 us; speedup vs baseline: 1.5400x; 1.0086x over previous
//
#include <hip/hip_runtime.h>
#include <type_traits>

// Shapes (fixed by the problem)
#define Bn 8
#define Tn 2048
#define Cn 1024
#define Hn 128
#define Mn (Bn*Tn)   // 16384

typedef __attribute__((ext_vector_type(4))) float f32x4;
typedef __attribute__((ext_vector_type(2))) float f32x2;
typedef __attribute__((ext_vector_type(16))) float f32x16;
typedef __attribute__((ext_vector_type(8))) short s16x8;
typedef __attribute__((ext_vector_type(4))) int i32x4;
typedef __attribute__((ext_vector_type(2))) int i32x2;
typedef unsigned int u32;

__device__ __forceinline__ unsigned short f2bf(float f) {
  union { float f; unsigned u; } v; v.f = f;
  unsigned r = v.u + 0x7FFFu + ((v.u >> 16) & 1u);   // RNE
  return (unsigned short)(r >> 16);
}

__device__ __forceinline__ float bf2f(unsigned s) {
  return __builtin_bit_cast(float, s << 16);
}

__device__ __forceinline__ unsigned cvtpk(float lo, float hi) {
  unsigned r;
  asm("v_cvt_pk_bf16_f32 %0, %1, %2" : "=v"(r) : "v"(lo), "v"(hi));
  return r;
}

// swap32(a,b): r0 = {a.lanes[0:31], b.lanes[0:31]}, r1 = {a.lanes[32:63], b.lanes[32:63]}
__device__ __forceinline__ i32x2 swap32(int a, int b) {
#if __has_builtin(__builtin_amdgcn_permlane32_swap)
  return __builtin_amdgcn_permlane32_swap(a, b, false, false);
#else
  int ax = __shfl_xor(a, 32), bx = __shfl_xor(b, 32);
  i32x2 r;
  r[0] = (threadIdx.x & 32) ? bx : a;
  r[1] = (threadIdx.x & 32) ? b : ax;
  return r;
#endif
}

__device__ __forceinline__ void gl_lds16(const void* g, void* l) {
  __builtin_amdgcn_global_load_lds((const __attribute__((address_space(1))) u32*)g,
                                   (__attribute__((address_space(3))) u32*)l, 16, 0, 0);
}

// ---------------------------------------------------------------------------
// Kernel 1: W [C,H] fp32 -> Wt [3][H][C] = [384][1024] bf16 (Wq scaled by 1/32)
// ---------------------------------------------------------------------------
__global__ __launch_bounds__(256) void prep_wt(const float* __restrict__ Wq,
                                               const float* __restrict__ Wk,
                                               const float* __restrict__ Wv,
                                               unsigned short* __restrict__ Wt) {
  __shared__ float tile[64][33];
  const int w = blockIdx.z;
  const float* W = (w == 0) ? Wq : (w == 1) ? Wk : Wv;
  const float scale = (w == 0) ? 0.03125f : 1.0f;   // C^-0.5 folded into Wq (exact pow2)
  const int c0 = blockIdx.x * 64, h0 = blockIdx.y * 32;
  const int tid = threadIdx.x;
  const int hl = tid & 31, cg = tid >> 5;
#pragma unroll
  for (int i = 0; i < 8; i++) {
    int cl = cg * 8 + i;
    tile[cl][hl] = W[(c0 + cl) * Hn + h0 + hl];
  }
  __syncthreads();
  const int cl2 = tid & 63, hg = tid >> 6;
#pragma unroll
  for (int i = 0; i < 8; i++) {
    int hl2 = hg * 8 + i;
    Wt[(size_t)(w * Hn + h0 + hl2) * Cn + c0 + cl2] = f2bf(tile[cl2][hl2] * scale);
  }
}

// ---------------------------------------------------------------------------
// Kernel 2: FUSED QKV projection, v6 = counted-vmcnt schedule, RACE-FIXED.
// BM=64, BN=384, BK=64, 8 waves (2m x 4n, 32x96/wave), 32x32x16 MFMA.
// Per step: barrier_A (all reads of buf P^1 done) -> issue t+1 staging into
// P^1 (2 A loads + 6 B gl_lds) -> vmcnt(8)+lgkmcnt(0) (waits step-t staging
// only) -> barrier_B -> compute on buf P -> writeA(P^1). The just-issued 8
// loads stay in flight across barrier_B; no vmcnt(0) drain in the loop.
// q,k -> [b][t][h]; v -> [b][h][t].
// ---------------------------------------------------------------------------
__global__ __launch_bounds__(512, 1) void proj_fused(const float* __restrict__ x,
                                                     const unsigned short* __restrict__ Wt,
                                                     unsigned short* __restrict__ qkv) {
  __shared__ __align__(16) unsigned short Abuf[2][64 * 64];    // 2 x 8 KB
  __shared__ __align__(16) unsigned short Bbuf[2][384 * 64];   // 2 x 48 KB
  const int tid = threadIdx.x;
  const int lane = tid & 63, wv = tid >> 6;   // 8 waves
  const int wm = wv >> 2, wn = wv & 3;        // wave tile: rows wm*32, cols wn*96
  const int l31 = lane & 31, hi = lane >> 5;
  const int bm = blockIdx.x * 64;

  // A-staging geometry (512 threads, 64x64 tile, 8 fp32 each)
  const int ar = tid >> 3;                    // row 0..63
  const int as = tid & 7;                     // 8-float chunk

  f32x16 acc[3];
#pragma unroll
  for (int i = 0; i < 3; i++)
#pragma unroll
    for (int r = 0; r < 16; r++) acc[i][r] = 0.f;

  auto stageB = [&](int buf, int kk) {
#pragma unroll
    for (int i = 0; i < 6; i++) {
      int r0 = wv * 48 + i * 8;
      int n = r0 + (lane >> 3);
      const unsigned short* src = Wt + (size_t)n * Cn + kk + (((lane & 7) ^ (n & 7)) << 3);
      gl_lds16(src, &Bbuf[buf][r0 * 64]);     // dest wave-uniform; +lane*16B implicit
    }
  };
  auto loadA = [&](int kk, float4& v0, float4& v1) {
    const float* g = x + (size_t)(bm + ar) * Cn + kk + as * 8;
    v0 = *(const float4*)g;
    v1 = *(const float4*)(g + 4);
  };
  auto writeA = [&](int buf, float4 v0, float4 v1) {
    i32x4 w = {(int)cvtpk(v0.x, v0.y), (int)cvtpk(v0.z, v0.w),
               (int)cvtpk(v1.x, v1.y), (int)cvtpk(v1.z, v1.w)};
    *(i32x4*)&Abuf[buf][ar * 64 + ((as ^ (ar & 7)) << 3)] = w;
  };

  // prologue: stage K-step 0 (2 A loads + 6 gl_lds; compiler waits A before write)
  {
    float4 a0, a1;
    loadA(0, a0, a1);
    stageB(0, 0);
    writeA(0, a0, a1);
  }

  const int arow = wm * 32 + l31;

  auto body = [&](int t, auto PC) {
    constexpr int P = decltype(PC)::value;    // cur buffer
    const bool more = (t < 15);
    // barrier_A: every wave has finished READING buf P^1 (step t-1's compute)
    __builtin_amdgcn_s_barrier();
    float4 a0, a1;
    if (more) {
      loadA((t + 1) * 64, a0, a1);            // 2 vm
      stageB(P ^ 1, (t + 1) * 64);            // 6 vm (gl_lds) -- safe: after barrier_A
      // wait only ops OLDER than my 8 (= step t's staging); publish A ds_writes
      asm volatile("s_waitcnt vmcnt(8) lgkmcnt(0)" ::: "memory");
    } else {
      asm volatile("s_waitcnt vmcnt(0) lgkmcnt(0)" ::: "memory");
    }
    __builtin_amdgcn_s_barrier();             // barrier_B: buf P staged for all waves
    __builtin_amdgcn_sched_barrier(0);
    // compute on buf P
    s16x8 aF[4];
#pragma unroll
    for (int ks = 0; ks < 4; ks++)
      aF[ks] = *(const s16x8*)&Abuf[P][arow * 64 + (((ks * 2 + hi) ^ (arow & 7)) << 3)];
    __builtin_amdgcn_s_setprio(1);
#pragma unroll
    for (int ks = 0; ks < 4; ks++)
#pragma unroll
      for (int ni = 0; ni < 3; ni++) {
        int brow = wn * 96 + ni * 32 + l31;
        s16x8 bF = *(const s16x8*)&Bbuf[P][brow * 64 + (((ks * 2 + hi) ^ (brow & 7)) << 3)];
        acc[ni] = __builtin_amdgcn_mfma_f32_32x32x16_bf16(aF[ks], bF, acc[ni], 0, 0, 0);
      }
    __builtin_amdgcn_s_setprio(0);
    if (more) writeA(P ^ 1, a0, a1);          // compiler inserts exact vmcnt for A loads
  };

  for (int t = 0; t < 16; t += 2) {
    body(t, std::integral_constant<int, 0>{});
    body(t + 1, std::integral_constant<int, 1>{});
  }

  // epilogue: D layout col=l31, row=(r&3)+8*(r>>2)+4*hi
#pragma unroll
  for (int ni = 0; ni < 3; ni++) {
    const int cb = wn * 3 + ni;               // 32-col block 0..11
    if (cb < 8) {                             // q (0-3) / k (4-7): [b][t][h]
      const int w = cb >> 2;
      const int h = (cb & 3) * 32 + l31;
      unsigned short* o = qkv + (size_t)w * ((size_t)Mn * Hn);
#pragma unroll
      for (int r = 0; r < 16; r++) {
        int m = bm + wm * 32 + (r & 3) + 8 * (r >> 2) + 4 * hi;
        o[(size_t)m * Hn + h] = f2bf(acc[ni][r]);
      }
    } else {                                  // v: transposed [b][h][t]
      const int h = (cb - 8) * 32 + l31;
      const int bb = bm >> 11;
      const int tl0 = (bm & 2047) + wm * 32;
      unsigned short* vt = qkv + (size_t)2 * Mn * Hn + (size_t)bb * (Hn * Tn) + (size_t)h * Tn;
#pragma unroll
      for (int r = 0; r < 16; r++)
        vt[tl0 + (r & 3) + 8 * (r >> 2) + 4 * hi] = f2bf(acc[ni][r]);
    }
  }
}

// ---------------------------------------------------------------------------
// Kernel 3: causal flash attention. 4 waves/block, 128 q-rows/block (32/wave),
// KVBLK=64 staged in LDS (XOR-swizzled, global_load_lds, double-buffered,
// 2-phase). Swapped 32x32 MFMA, in-register softmax. KV-split S chunks with
// complementary q-tile pairing. Partials (bf16 o, f32 m/l) to workspace.
// ---------------------------------------------------------------------------
__global__ __launch_bounds__(256, 2) void attn_fwd(const unsigned short* __restrict__ qkv,
                                                   unsigned short* __restrict__ o_part,
                                                   float* __restrict__ ml,
                                                   int sshift) {
  __shared__ __align__(16) unsigned short Kl[2][64 * 128];  // [kv][h] 16KB x2
  __shared__ __align__(16) unsigned short Vl[2][128 * 64];  // [h][kv] 16KB x2

  const int bid = blockIdx.x;
  const int b = bid & 7;                    // batch -> XCD pin
  const int r = bid >> 3;
  const int jj = r & 15;
  const int sp = r >> 4;
  const int S = 1 << sshift;
  const int j = (S > 1 && sp >= (S >> 1)) ? (15 - jj) : jj;   // complementary pairing
  const int s = sp;

  const int tid = threadIdx.x;
  const int lane = tid & 63, wv = tid >> 6;   // 4 waves
  const int l31 = lane & 31, hi = lane >> 5;

  const unsigned short* qb  = qkv + (size_t)b * (Tn * Hn);
  const unsigned short* kb  = qkv + (size_t)(Mn * Hn) + (size_t)b * (Tn * Hn);
  const unsigned short* vtb = qkv + (size_t)2 * (Mn * Hn) + (size_t)b * (Hn * Tn);

  const int qrow0 = j * 128 + wv * 32;      // this wave's 32 q-rows
  const int qg = qrow0 + l31;               // this lane's q-row

  const int ntt = (j + 1) * 2;              // kv tiles of 64 for this q-tile
  const int tlo = (s * ntt) >> sshift;
  const int thi = ((s + 1) * ntt) >> sshift;

  f32x16 oT[4];
#pragma unroll
  for (int i = 0; i < 4; i++)
#pragma unroll
    for (int q = 0; q < 16; q++) oT[i][q] = 0.f;
  float m_ = -1e30f, l_ = 0.f;

  auto stage = [&](int buf, int tile) {
    const int kvb0 = tile * 64;
#pragma unroll
    for (int i = 0; i < 4; i++) {
      int r0 = wv * 16 + i * 4;
      int row = r0 + (lane >> 4);
      int ch = lane & 15;
      const unsigned short* src = kb + (size_t)(kvb0 + row) * Hn + ((ch ^ (row & 7)) << 3);
      gl_lds16(src, &Kl[buf][r0 * 128]);
    }
#pragma unroll
    for (int i = 0; i < 4; i++) {
      int r0 = wv * 32 + i * 8;
      int row = r0 + (lane >> 3);
      int ch = lane & 7;
      const unsigned short* src = vtb + (size_t)row * Tn + kvb0 + ((ch ^ (row & 7)) << 3);
      gl_lds16(src, &Vl[buf][r0 * 64]);
    }
  };

  if (tlo < thi) {
    // Q B-fragments: n=q=l31, k = hs*16 + hi*8 + jx
    s16x8 qB[8];
#pragma unroll
    for (int hs = 0; hs < 8; hs++)
      qB[hs] = *(const s16x8*)(qb + (size_t)qg * Hn + hs * 16 + hi * 8);

    stage(0, tlo);
    asm volatile("s_waitcnt vmcnt(0)");
    __syncthreads();
    int buf = 0;

    for (int t = tlo; t < thi; t++) {
      if (t + 1 < thi) stage(buf ^ 1, t + 1);   // loads in flight over compute
      const int kvb = t * 64;
      if (kvb < qrow0 + 32) {                   // wave not fully above diagonal
        const unsigned short* Kb = &Kl[buf][0];
        // ---- S^T = K Q^T (two 32-kv halves) ----
        f32x16 sv0, sv1;
#pragma unroll
        for (int q = 0; q < 16; q++) { sv0[q] = 0.f; sv1[q] = 0.f; }
        __builtin_amdgcn_s_setprio(1);
        {
          const int row = l31;
#pragma unroll
          for (int hs = 0; hs < 8; hs++) {
            s16x8 kf = *(const s16x8*)&Kb[row * 128 + (((hs * 2 + hi) ^ (row & 7)) << 3)];
            sv0 = __builtin_amdgcn_mfma_f32_32x32x16_bf16(kf, qB[hs], sv0, 0, 0, 0);
          }
        }
        {
          const int row = 32 + l31;
#pragma unroll
          for (int hs = 0; hs < 8; hs++) {
            s16x8 kf = *(const s16x8*)&Kb[row * 128 + (((hs * 2 + hi) ^ (row & 7)) << 3)];
            sv1 = __builtin_amdgcn_mfma_f32_32x32x16_bf16(kf, qB[hs], sv1, 0, 0, 0);
          }
        }
        __builtin_amdgcn_s_setprio(0);
        // ---- causal mask (diagonal-adjacent tiles only) ----
        if (kvb + 63 > qrow0) {
#pragma unroll
          for (int q = 0; q < 16; q++) {
            int kr = (q & 3) + 8 * (q >> 2) + 4 * hi;
            if (kvb + kr > qg) sv0[q] = -1e30f;
            if (kvb + 32 + kr > qg) sv1[q] = -1e30f;
          }
        }
        // ---- online softmax (row = per-lane) ----
        float om = sv0[0];
#pragma unroll
        for (int q = 1; q < 16; q++) om = fmaxf(om, sv0[q]);
#pragma unroll
        for (int q = 0; q < 16; q++) om = fmaxf(om, sv1[q]);
        i32x2 mx = swap32(__builtin_bit_cast(int, om), __builtin_bit_cast(int, om));
        float pm = __builtin_bit_cast(float, hi ? mx[0] : mx[1]);
        float tmax = fmaxf(om, pm);
        if (__any(tmax > m_ + 8.f)) {           // deferred rescale (T13)
          float mn = fmaxf(m_, tmax);
          float sc = __expf(m_ - mn);
          m_ = mn; l_ *= sc;
#pragma unroll
          for (int i = 0; i < 4; i++)
#pragma unroll
            for (int q = 0; q < 16; q++) oT[i][q] *= sc;
        }
        float osum = 0.f;
#pragma unroll
        for (int q = 0; q < 16; q++) { sv0[q] = __expf(sv0[q] - m_); osum += sv0[q]; }
#pragma unroll
        for (int q = 0; q < 16; q++) { sv1[q] = __expf(sv1[q] - m_); osum += sv1[q]; }
        i32x2 sx = swap32(__builtin_bit_cast(int, osum), __builtin_bit_cast(int, osum));
        float psum = __builtin_bit_cast(float, hi ? sx[0] : sx[1]);
        l_ += osum + psum;
        // ---- pack P^T to bf16 B-fragments (T12) ----
        s16x8 pB[4];
        {
          unsigned PK[8];
#pragma unroll
          for (int n = 0; n < 8; n++) PK[n] = cvtpk(sv0[2 * n], sv0[2 * n + 1]);
          i32x2 e0 = swap32((int)PK[0], (int)PK[2]);
          i32x2 e1 = swap32((int)PK[1], (int)PK[3]);
          i32x2 e2 = swap32((int)PK[4], (int)PK[6]);
          i32x2 e3 = swap32((int)PK[5], (int)PK[7]);
          i32x4 w0 = {e0[0], e1[0], e0[1], e1[1]};
          i32x4 w1 = {e2[0], e3[0], e2[1], e3[1]};
          pB[0] = __builtin_bit_cast(s16x8, w0);
          pB[1] = __builtin_bit_cast(s16x8, w1);
        }
        {
          unsigned PK[8];
#pragma unroll
          for (int n = 0; n < 8; n++) PK[n] = cvtpk(sv1[2 * n], sv1[2 * n + 1]);
          i32x2 e0 = swap32((int)PK[0], (int)PK[2]);
          i32x2 e1 = swap32((int)PK[1], (int)PK[3]);
          i32x2 e2 = swap32((int)PK[4], (int)PK[6]);
          i32x2 e3 = swap32((int)PK[5], (int)PK[7]);
          i32x4 w0 = {e0[0], e1[0], e0[1], e1[1]};
          i32x4 w1 = {e2[0], e3[0], e2[1], e3[1]};
          pB[2] = __builtin_bit_cast(s16x8, w0);
          pB[3] = __builtin_bit_cast(s16x8, w1);
        }
        // ---- O^T += V^T P^T ----
        __builtin_amdgcn_s_setprio(1);
#pragma unroll
        for (int hsl = 0; hsl < 4; hsl++) {
          const int row = hsl * 32 + l31;
#pragma unroll
          for (int ks = 0; ks < 4; ks++) {
            s16x8 vf = *(const s16x8*)&Vl[buf][row * 64 + (((ks * 2 + hi) ^ (row & 7)) << 3)];
            oT[hsl] = __builtin_amdgcn_mfma_f32_32x32x16_bf16(vf, pB[ks], oT[hsl], 0, 0, 0);
          }
        }
        __builtin_amdgcn_s_setprio(0);
      }
      asm volatile("s_waitcnt vmcnt(0)");       // staged t+1 landed
      __syncthreads();                          // cur fully consumed by all waves
      buf ^= 1;
    }
  }

  // epilogue: bf16 partials. o_part[s][row][h], h = hsl*32 + (q&3)+8*(q>>2)+4*hi
  unsigned short* orow = o_part + (size_t)s * ((size_t)Mn * Hn) + (size_t)(b * Tn + qg) * Hn;
#pragma unroll
  for (int hsl = 0; hsl < 4; hsl++)
#pragma unroll
    for (int g = 0; g < 4; g++) {
      unsigned p0 = cvtpk(oT[hsl][4 * g + 0], oT[hsl][4 * g + 1]);
      unsigned p1 = cvtpk(oT[hsl][4 * g + 2], oT[hsl][4 * g + 3]);
      i32x2 st = {(int)p0, (int)p1};
      *(i32x2*)(orow + hsl * 32 + g * 8 + hi * 4) = st;
    }
  if (lane < 32) {
    f32x2 w = {m_, l_};
    *(f32x2*)(ml + (size_t)s * (Mn * 2) + (size_t)(b * Tn + qg) * 2) = w;
  }
}

// ---------------------------------------------------------------------------
// Kernel 4: combine bf16 KV-split partials (fp32 accumulation).
// 256 threads: 4 q-rows/block, each thread handles 2 adjacent h.
// ---------------------------------------------------------------------------
__global__ __launch_bounds__(256) void combine(const unsigned short* __restrict__ o_part,
                                               const float* __restrict__ ml,
                                               float* __restrict__ out, int S) {
  const int q = blockIdx.x * 4 + (threadIdx.x >> 6);
  const int p = threadIdx.x & 63;           // h pair: 2p, 2p+1
  float M = -1e30f;
  for (int s = 0; s < S; s++) M = fmaxf(M, ml[(size_t)s * (Mn * 2) + q * 2]);
  float L = 0.f, a0 = 0.f, a1 = 0.f;
  for (int s = 0; s < S; s++) {
    float ms = ml[(size_t)s * (Mn * 2) + q * 2];
    float ls = ml[(size_t)s * (Mn * 2) + q * 2 + 1];
    float w = __expf(ms - M);
    L += ls * w;
    u32 v = *(const u32*)(o_part + (size_t)s * ((size_t)Mn * Hn) + (size_t)q * Hn + p * 2);
    a0 += bf2f(v & 0xffffu) * w;
    a1 += bf2f(v >> 16) * w;
  }
  float2 o = {a0 / L, a1 / L};
  *(float2*)(out + (size_t)q * Hn + p * 2) = o;
}

// ---------------------------------------------------------------------------
extern "C" void kernel_launch(void* const* d_in, const int* in_sizes, int n_in,
                              void* d_out, int out_size, void* d_ws, size_t ws_size,
                              hipStream_t stream) {
  const float* x  = (const float*)d_in[0];
  const float* Wk = (const float*)d_in[1];
  const float* Wq = (const float*)d_in[2];
  const float* Wv = (const float*)d_in[3];
  float* out = (float*)d_out;

  char* ws = (char*)d_ws;
  const size_t wt_b  = 786432;                      // 3*128*1024*2
  const size_t qkv_b = (size_t)3 * Mn * Hn * 2;     // 12.58 MB
  const size_t base  = wt_b + qkv_b;
  const size_t per   = (size_t)Mn * Hn * 2 + (size_t)Mn * 8;  // bf16 o + f32 ml
  int sshift = (ws_size >= base + 4 * per) ? 2 : (ws_size >= base + 2 * per) ? 1 : 0;
  const int S = 1 << sshift;

  unsigned short* Wt  = (unsigned short*)ws;
  unsigned short* qkv = (unsigned short*)(ws + wt_b);
  unsigned short* o_part = (unsigned short*)(ws + base);
  float* mlp = (float*)(ws + base + (size_t)S * Mn * Hn * 2);

  prep_wt<<<dim3(16, 4, 3), 256, 0, stream>>>(Wq, Wk, Wv, Wt);
  proj_fused<<<256, 512, 0, stream>>>(x, Wt, qkv);
  attn_fwd<<<128 * S, 256, 0, stream>>>(qkv, o_part, mlp, sshift);
  combine<<<Mn / 4, 256, 0, stream>>>(o_part, mlp, out, S);
}

// Round 11
// 63.505 us; speedup vs baseline: 1.6237x; 1.0543x over previous
//
#include <hip/hip_runtime.h>
#include <type_traits>

// Shapes (fixed by the problem)
#define Bn 8
#define Tn 2048
#define Cn 1024
#define Hn 128
#define Mn (Bn*Tn)   // 16384

typedef __attribute__((ext_vector_type(4))) float f32x4;
typedef __attribute__((ext_vector_type(2))) float f32x2;
typedef __attribute__((ext_vector_type(16))) float f32x16;
typedef __attribute__((ext_vector_type(8))) short s16x8;
typedef __attribute__((ext_vector_type(4))) int i32x4;
typedef __attribute__((ext_vector_type(2))) int i32x2;
typedef unsigned int u32;

__device__ __forceinline__ unsigned short f2bf(float f) {
  union { float f; unsigned u; } v; v.f = f;
  unsigned r = v.u + 0x7FFFu + ((v.u >> 16) & 1u);   // RNE
  return (unsigned short)(r >> 16);
}

__device__ __forceinline__ float bf2f(unsigned s) {
  return __builtin_bit_cast(float, s << 16);
}

__device__ __forceinline__ unsigned cvtpk(float lo, float hi) {
  unsigned r;
  asm("v_cvt_pk_bf16_f32 %0, %1, %2" : "=v"(r) : "v"(lo), "v"(hi));
  return r;
}

// swap32(a,b): r0 = {a.lanes[0:31], b.lanes[0:31]}, r1 = {a.lanes[32:63], b.lanes[32:63]}
__device__ __forceinline__ i32x2 swap32(int a, int b) {
#if __has_builtin(__builtin_amdgcn_permlane32_swap)
  return __builtin_amdgcn_permlane32_swap(a, b, false, false);
#else
  int ax = __shfl_xor(a, 32), bx = __shfl_xor(b, 32);
  i32x2 r;
  r[0] = (threadIdx.x & 32) ? bx : a;
  r[1] = (threadIdx.x & 32) ? b : ax;
  return r;
#endif
}

__device__ __forceinline__ void gl_lds16(const void* g, void* l) {
  __builtin_amdgcn_global_load_lds((const __attribute__((address_space(1))) u32*)g,
                                   (__attribute__((address_space(3))) u32*)l, 16, 0, 0);
}

// ---------------------------------------------------------------------------
// Kernel 1: W [C,H] fp32 -> Wt [3][H][C] = [384][1024] bf16 (Wq scaled by 1/32)
// ---------------------------------------------------------------------------
__global__ __launch_bounds__(256) void prep_wt(const float* __restrict__ Wq,
                                               const float* __restrict__ Wk,
                                               const float* __restrict__ Wv,
                                               unsigned short* __restrict__ Wt) {
  __shared__ float tile[64][33];
  const int w = blockIdx.z;
  const float* W = (w == 0) ? Wq : (w == 1) ? Wk : Wv;
  const float scale = (w == 0) ? 0.03125f : 1.0f;   // C^-0.5 folded into Wq (exact pow2)
  const int c0 = blockIdx.x * 64, h0 = blockIdx.y * 32;
  const int tid = threadIdx.x;
  const int hl = tid & 31, cg = tid >> 5;
#pragma unroll
  for (int i = 0; i < 8; i++) {
    int cl = cg * 8 + i;
    tile[cl][hl] = W[(c0 + cl) * Hn + h0 + hl];
  }
  __syncthreads();
  const int cl2 = tid & 63, hg = tid >> 6;
#pragma unroll
  for (int i = 0; i < 8; i++) {
    int hl2 = hg * 8 + i;
    Wt[(size_t)(w * Hn + h0 + hl2) * Cn + c0 + cl2] = f2bf(tile[cl2][hl2] * scale);
  }
}

// ---------------------------------------------------------------------------
// Kernel 2: FUSED QKV projection, v7 = v6 + K-LOOP STAGGER.
// All 256 blocks used to read the SAME 48 KB Wt slice in lockstep ->
// same-address L2 serialization (invariant ~41 us across rounds 4-10).
// Stagger: block processes K-slices ((u + phase) & 15), phase=(bid>>3)&15,
// so same-XCD blocks touch 16 distinct slices at any instant. fp32 acc is
// order-independent. A-loads issued pre-barrier (regs only, no LDS hazard).
// BM=64, BN=384, BK=64, 8 waves (2m x 4n); race-fixed counted-vmcnt loop.
// q,k -> [b][t][h]; v -> [b][h][t].
// ---------------------------------------------------------------------------
__global__ __launch_bounds__(512, 1) void proj_fused(const float* __restrict__ x,
                                                     const unsigned short* __restrict__ Wt,
                                                     unsigned short* __restrict__ qkv) {
  __shared__ __align__(16) unsigned short Abuf[2][64 * 64];    // 2 x 8 KB
  __shared__ __align__(16) unsigned short Bbuf[2][384 * 64];   // 2 x 48 KB
  const int tid = threadIdx.x;
  const int lane = tid & 63, wv = tid >> 6;   // 8 waves
  const int wm = wv >> 2, wn = wv & 3;        // wave tile: rows wm*32, cols wn*96
  const int l31 = lane & 31, hi = lane >> 5;
  const int bm = blockIdx.x * 64;
  const int phase = (blockIdx.x >> 3) & 15;   // same-XCD neighbors get distinct phases

  // A-staging geometry (512 threads, 64x64 tile, 8 fp32 each)
  const int ar = tid >> 3;                    // row 0..63
  const int as = tid & 7;                     // 8-float chunk

  f32x16 acc[3];
#pragma unroll
  for (int i = 0; i < 3; i++)
#pragma unroll
    for (int r = 0; r < 16; r++) acc[i][r] = 0.f;

  auto slice = [&](int u) { return ((u + phase) & 15) * 64; };

  auto stageB = [&](int buf, int kk) {
#pragma unroll
    for (int i = 0; i < 6; i++) {
      int r0 = wv * 48 + i * 8;
      int n = r0 + (lane >> 3);
      const unsigned short* src = Wt + (size_t)n * Cn + kk + (((lane & 7) ^ (n & 7)) << 3);
      gl_lds16(src, &Bbuf[buf][r0 * 64]);     // dest wave-uniform; +lane*16B implicit
    }
  };
  auto loadA = [&](int kk, float4& v0, float4& v1) {
    const float* g = x + (size_t)(bm + ar) * Cn + kk + as * 8;
    v0 = *(const float4*)g;
    v1 = *(const float4*)(g + 4);
  };
  auto writeA = [&](int buf, float4 v0, float4 v1) {
    i32x4 w = {(int)cvtpk(v0.x, v0.y), (int)cvtpk(v0.z, v0.w),
               (int)cvtpk(v1.x, v1.y), (int)cvtpk(v1.z, v1.w)};
    *(i32x4*)&Abuf[buf][ar * 64 + ((as ^ (ar & 7)) << 3)] = w;
  };

  // prologue: stage logical step 0 (= physical slice(0))
  {
    float4 a0, a1;
    loadA(slice(0), a0, a1);
    stageB(0, slice(0));
    writeA(0, a0, a1);
  }

  const int arow = wm * 32 + l31;

  auto body = [&](int u, auto PC) {
    constexpr int P = decltype(PC)::value;    // cur buffer
    const bool more = (u < 15);
    float4 a0, a1;
    if (more) loadA(slice(u + 1), a0, a1);    // regs only -- safe pre-barrier
    // barrier_A: every wave has finished READING buf P^1 (step u-1's compute)
    __builtin_amdgcn_s_barrier();
    if (more) {
      stageB(P ^ 1, slice(u + 1));            // 6 vm (gl_lds) -- after barrier_A
      // wait only ops OLDER than my 8 (2 A + 6 B) = step u's staging
      asm volatile("s_waitcnt vmcnt(8) lgkmcnt(0)" ::: "memory");
    } else {
      asm volatile("s_waitcnt vmcnt(0) lgkmcnt(0)" ::: "memory");
    }
    __builtin_amdgcn_s_barrier();             // barrier_B: buf P staged for all waves
    __builtin_amdgcn_sched_barrier(0);
    // compute on buf P
    s16x8 aF[4];
#pragma unroll
    for (int ks = 0; ks < 4; ks++)
      aF[ks] = *(const s16x8*)&Abuf[P][arow * 64 + (((ks * 2 + hi) ^ (arow & 7)) << 3)];
    __builtin_amdgcn_s_setprio(1);
#pragma unroll
    for (int ks = 0; ks < 4; ks++)
#pragma unroll
      for (int ni = 0; ni < 3; ni++) {
        int brow = wn * 96 + ni * 32 + l31;
        s16x8 bF = *(const s16x8*)&Bbuf[P][brow * 64 + (((ks * 2 + hi) ^ (brow & 7)) << 3)];
        acc[ni] = __builtin_amdgcn_mfma_f32_32x32x16_bf16(aF[ks], bF, acc[ni], 0, 0, 0);
      }
    __builtin_amdgcn_s_setprio(0);
    if (more) writeA(P ^ 1, a0, a1);          // compiler inserts exact vmcnt for A loads
  };

  for (int u = 0; u < 16; u += 2) {
    body(u, std::integral_constant<int, 0>{});
    body(u + 1, std::integral_constant<int, 1>{});
  }

  // epilogue: D layout col=l31, row=(r&3)+8*(r>>2)+4*hi
#pragma unroll
  for (int ni = 0; ni < 3; ni++) {
    const int cb = wn * 3 + ni;               // 32-col block 0..11
    if (cb < 8) {                             // q (0-3) / k (4-7): [b][t][h]
      const int w = cb >> 2;
      const int h = (cb & 3) * 32 + l31;
      unsigned short* o = qkv + (size_t)w * ((size_t)Mn * Hn);
#pragma unroll
      for (int r = 0; r < 16; r++) {
        int m = bm + wm * 32 + (r & 3) + 8 * (r >> 2) + 4 * hi;
        o[(size_t)m * Hn + h] = f2bf(acc[ni][r]);
      }
    } else {                                  // v: transposed [b][h][t]
      const int h = (cb - 8) * 32 + l31;
      const int bb = bm >> 11;
      const int tl0 = (bm & 2047) + wm * 32;
      unsigned short* vt = qkv + (size_t)2 * Mn * Hn + (size_t)bb * (Hn * Tn) + (size_t)h * Tn;
#pragma unroll
      for (int r = 0; r < 16; r++)
        vt[tl0 + (r & 3) + 8 * (r >> 2) + 4 * hi] = f2bf(acc[ni][r]);
    }
  }
}

// ---------------------------------------------------------------------------
// Kernel 3: causal flash attention. 4 waves/block, 128 q-rows/block (32/wave),
// KVBLK=64 staged in LDS (XOR-swizzled, global_load_lds, double-buffered,
// 2-phase). Swapped 32x32 MFMA, in-register softmax. KV-split S chunks with
// complementary q-tile pairing. Partials (bf16 o, f32 m/l) to workspace.
// ---------------------------------------------------------------------------
__global__ __launch_bounds__(256, 2) void attn_fwd(const unsigned short* __restrict__ qkv,
                                                   unsigned short* __restrict__ o_part,
                                                   float* __restrict__ ml,
                                                   int sshift) {
  __shared__ __align__(16) unsigned short Kl[2][64 * 128];  // [kv][h] 16KB x2
  __shared__ __align__(16) unsigned short Vl[2][128 * 64];  // [h][kv] 16KB x2

  const int bid = blockIdx.x;
  const int b = bid & 7;                    // batch -> XCD pin
  const int r = bid >> 3;
  const int jj = r & 15;
  const int sp = r >> 4;
  const int S = 1 << sshift;
  const int j = (S > 1 && sp >= (S >> 1)) ? (15 - jj) : jj;   // complementary pairing
  const int s = sp;

  const int tid = threadIdx.x;
  const int lane = tid & 63, wv = tid >> 6;   // 4 waves
  const int l31 = lane & 31, hi = lane >> 5;

  const unsigned short* qb  = qkv + (size_t)b * (Tn * Hn);
  const unsigned short* kb  = qkv + (size_t)(Mn * Hn) + (size_t)b * (Tn * Hn);
  const unsigned short* vtb = qkv + (size_t)2 * (Mn * Hn) + (size_t)b * (Hn * Tn);

  const int qrow0 = j * 128 + wv * 32;      // this wave's 32 q-rows
  const int qg = qrow0 + l31;               // this lane's q-row

  const int ntt = (j + 1) * 2;              // kv tiles of 64 for this q-tile
  const int tlo = (s * ntt) >> sshift;
  const int thi = ((s + 1) * ntt) >> sshift;

  f32x16 oT[4];
#pragma unroll
  for (int i = 0; i < 4; i++)
#pragma unroll
    for (int q = 0; q < 16; q++) oT[i][q] = 0.f;
  float m_ = -1e30f, l_ = 0.f;

  auto stage = [&](int buf, int tile) {
    const int kvb0 = tile * 64;
#pragma unroll
    for (int i = 0; i < 4; i++) {
      int r0 = wv * 16 + i * 4;
      int row = r0 + (lane >> 4);
      int ch = lane & 15;
      const unsigned short* src = kb + (size_t)(kvb0 + row) * Hn + ((ch ^ (row & 7)) << 3);
      gl_lds16(src, &Kl[buf][r0 * 128]);
    }
#pragma unroll
    for (int i = 0; i < 4; i++) {
      int r0 = wv * 32 + i * 8;
      int row = r0 + (lane >> 3);
      int ch = lane & 7;
      const unsigned short* src = vtb + (size_t)row * Tn + kvb0 + ((ch ^ (row & 7)) << 3);
      gl_lds16(src, &Vl[buf][r0 * 64]);
    }
  };

  if (tlo < thi) {
    // Q B-fragments: n=q=l31, k = hs*16 + hi*8 + jx
    s16x8 qB[8];
#pragma unroll
    for (int hs = 0; hs < 8; hs++)
      qB[hs] = *(const s16x8*)(qb + (size_t)qg * Hn + hs * 16 + hi * 8);

    stage(0, tlo);
    asm volatile("s_waitcnt vmcnt(0)");
    __syncthreads();
    int buf = 0;

    for (int t = tlo; t < thi; t++) {
      if (t + 1 < thi) stage(buf ^ 1, t + 1);   // loads in flight over compute
      const int kvb = t * 64;
      if (kvb < qrow0 + 32) {                   // wave not fully above diagonal
        const unsigned short* Kb = &Kl[buf][0];
        // ---- S^T = K Q^T (two 32-kv halves) ----
        f32x16 sv0, sv1;
#pragma unroll
        for (int q = 0; q < 16; q++) { sv0[q] = 0.f; sv1[q] = 0.f; }
        __builtin_amdgcn_s_setprio(1);
        {
          const int row = l31;
#pragma unroll
          for (int hs = 0; hs < 8; hs++) {
            s16x8 kf = *(const s16x8*)&Kb[row * 128 + (((hs * 2 + hi) ^ (row & 7)) << 3)];
            sv0 = __builtin_amdgcn_mfma_f32_32x32x16_bf16(kf, qB[hs], sv0, 0, 0, 0);
          }
        }
        {
          const int row = 32 + l31;
#pragma unroll
          for (int hs = 0; hs < 8; hs++) {
            s16x8 kf = *(const s16x8*)&Kb[row * 128 + (((hs * 2 + hi) ^ (row & 7)) << 3)];
            sv1 = __builtin_amdgcn_mfma_f32_32x32x16_bf16(kf, qB[hs], sv1, 0, 0, 0);
          }
        }
        __builtin_amdgcn_s_setprio(0);
        // ---- causal mask (diagonal-adjacent tiles only) ----
        if (kvb + 63 > qrow0) {
#pragma unroll
          for (int q = 0; q < 16; q++) {
            int kr = (q & 3) + 8 * (q >> 2) + 4 * hi;
            if (kvb + kr > qg) sv0[q] = -1e30f;
            if (kvb + 32 + kr > qg) sv1[q] = -1e30f;
          }
        }
        // ---- online softmax (row = per-lane) ----
        float om = sv0[0];
#pragma unroll
        for (int q = 1; q < 16; q++) om = fmaxf(om, sv0[q]);
#pragma unroll
        for (int q = 0; q < 16; q++) om = fmaxf(om, sv1[q]);
        i32x2 mx = swap32(__builtin_bit_cast(int, om), __builtin_bit_cast(int, om));
        float pm = __builtin_bit_cast(float, hi ? mx[0] : mx[1]);
        float tmax = fmaxf(om, pm);
        if (__any(tmax > m_ + 8.f)) {           // deferred rescale (T13)
          float mn = fmaxf(m_, tmax);
          float sc = __expf(m_ - mn);
          m_ = mn; l_ *= sc;
#pragma unroll
          for (int i = 0; i < 4; i++)
#pragma unroll
            for (int q = 0; q < 16; q++) oT[i][q] *= sc;
        }
        float osum = 0.f;
#pragma unroll
        for (int q = 0; q < 16; q++) { sv0[q] = __expf(sv0[q] - m_); osum += sv0[q]; }
#pragma unroll
        for (int q = 0; q < 16; q++) { sv1[q] = __expf(sv1[q] - m_); osum += sv1[q]; }
        i32x2 sx = swap32(__builtin_bit_cast(int, osum), __builtin_bit_cast(int, osum));
        float psum = __builtin_bit_cast(float, hi ? sx[0] : sx[1]);
        l_ += osum + psum;
        // ---- pack P^T to bf16 B-fragments (T12) ----
        s16x8 pB[4];
        {
          unsigned PK[8];
#pragma unroll
          for (int n = 0; n < 8; n++) PK[n] = cvtpk(sv0[2 * n], sv0[2 * n + 1]);
          i32x2 e0 = swap32((int)PK[0], (int)PK[2]);
          i32x2 e1 = swap32((int)PK[1], (int)PK[3]);
          i32x2 e2 = swap32((int)PK[4], (int)PK[6]);
          i32x2 e3 = swap32((int)PK[5], (int)PK[7]);
          i32x4 w0 = {e0[0], e1[0], e0[1], e1[1]};
          i32x4 w1 = {e2[0], e3[0], e2[1], e3[1]};
          pB[0] = __builtin_bit_cast(s16x8, w0);
          pB[1] = __builtin_bit_cast(s16x8, w1);
        }
        {
          unsigned PK[8];
#pragma unroll
          for (int n = 0; n < 8; n++) PK[n] = cvtpk(sv1[2 * n], sv1[2 * n + 1]);
          i32x2 e0 = swap32((int)PK[0], (int)PK[2]);
          i32x2 e1 = swap32((int)PK[1], (int)PK[3]);
          i32x2 e2 = swap32((int)PK[4], (int)PK[6]);
          i32x2 e3 = swap32((int)PK[5], (int)PK[7]);
          i32x4 w0 = {e0[0], e1[0], e0[1], e1[1]};
          i32x4 w1 = {e2[0], e3[0], e2[1], e3[1]};
          pB[2] = __builtin_bit_cast(s16x8, w0);
          pB[3] = __builtin_bit_cast(s16x8, w1);
        }
        // ---- O^T += V^T P^T ----
        __builtin_amdgcn_s_setprio(1);
#pragma unroll
        for (int hsl = 0; hsl < 4; hsl++) {
          const int row = hsl * 32 + l31;
#pragma unroll
          for (int ks = 0; ks < 4; ks++) {
            s16x8 vf = *(const s16x8*)&Vl[buf][row * 64 + (((ks * 2 + hi) ^ (row & 7)) << 3)];
            oT[hsl] = __builtin_amdgcn_mfma_f32_32x32x16_bf16(vf, pB[ks], oT[hsl], 0, 0, 0);
          }
        }
        __builtin_amdgcn_s_setprio(0);
      }
      asm volatile("s_waitcnt vmcnt(0)");       // staged t+1 landed
      __syncthreads();                          // cur fully consumed by all waves
      buf ^= 1;
    }
  }

  // epilogue: bf16 partials. o_part[s][row][h], h = hsl*32 + (q&3)+8*(q>>2)+4*hi
  unsigned short* orow = o_part + (size_t)s * ((size_t)Mn * Hn) + (size_t)(b * Tn + qg) * Hn;
#pragma unroll
  for (int hsl = 0; hsl < 4; hsl++)
#pragma unroll
    for (int g = 0; g < 4; g++) {
      unsigned p0 = cvtpk(oT[hsl][4 * g + 0], oT[hsl][4 * g + 1]);
      unsigned p1 = cvtpk(oT[hsl][4 * g + 2], oT[hsl][4 * g + 3]);
      i32x2 st = {(int)p0, (int)p1};
      *(i32x2*)(orow + hsl * 32 + g * 8 + hi * 4) = st;
    }
  if (lane < 32) {
    f32x2 w = {m_, l_};
    *(f32x2*)(ml + (size_t)s * (Mn * 2) + (size_t)(b * Tn + qg) * 2) = w;
  }
}

// ---------------------------------------------------------------------------
// Kernel 4: combine bf16 KV-split partials (fp32 accumulation).
// ---------------------------------------------------------------------------
__global__ __launch_bounds__(256) void combine(const unsigned short* __restrict__ o_part,
                                               const float* __restrict__ ml,
                                               float* __restrict__ out, int S) {
  const int q = blockIdx.x * 4 + (threadIdx.x >> 6);
  const int p = threadIdx.x & 63;           // h pair: 2p, 2p+1
  float M = -1e30f;
  for (int s = 0; s < S; s++) M = fmaxf(M, ml[(size_t)s * (Mn * 2) + q * 2]);
  float L = 0.f, a0 = 0.f, a1 = 0.f;
  for (int s = 0; s < S; s++) {
    float ms = ml[(size_t)s * (Mn * 2) + q * 2];
    float ls = ml[(size_t)s * (Mn * 2) + q * 2 + 1];
    float w = __expf(ms - M);
    L += ls * w;
    u32 v = *(const u32*)(o_part + (size_t)s * ((size_t)Mn * Hn) + (size_t)q * Hn + p * 2);
    a0 += bf2f(v & 0xffffu) * w;
    a1 += bf2f(v >> 16) * w;
  }
  float2 o = {a0 / L, a1 / L};
  *(float2*)(out + (size_t)q * Hn + p * 2) = o;
}

// ---------------------------------------------------------------------------
extern "C" void kernel_launch(void* const* d_in, const int* in_sizes, int n_in,
                              void* d_out, int out_size, void* d_ws, size_t ws_size,
                              hipStream_t stream) {
  const float* x  = (const float*)d_in[0];
  const float* Wk = (const float*)d_in[1];
  const float* Wq = (const float*)d_in[2];
  const float* Wv = (const float*)d_in[3];
  float* out = (float*)d_out;

  char* ws = (char*)d_ws;
  const size_t wt_b  = 786432;                      // 3*128*1024*2
  const size_t qkv_b = (size_t)3 * Mn * Hn * 2;     // 12.58 MB
  const size_t base  = wt_b + qkv_b;
  const size_t per   = (size_t)Mn * Hn * 2 + (size_t)Mn * 8;  // bf16 o + f32 ml
  int sshift = (ws_size >= base + 4 * per) ? 2 : (ws_size >= base + 2 * per) ? 1 : 0;
  const int S = 1 << sshift;

  unsigned short* Wt  = (unsigned short*)ws;
  unsigned short* qkv = (unsigned short*)(ws + wt_b);
  unsigned short* o_part = (unsigned short*)(ws + base);
  float* mlp = (float*)(ws + base + (size_t)S * Mn * Hn * 2);

  prep_wt<<<dim3(16, 4, 3), 256, 0, stream>>>(Wq, Wk, Wv, Wt);
  proj_fused<<<256, 512, 0, stream>>>(x, Wt, qkv);
  attn_fwd<<<128 * S, 256, 0, stream>>>(qkv, o_part, mlp, sshift);
  combine<<<Mn / 4, 256, 0, stream>>>(o_part, mlp, out, S);
}